// Round 1
// baseline (916.566 us; speedup 1.0000x reference)
//
#include <hip/hip_runtime.h>
#include <hip/hip_bf16.h>

typedef __attribute__((ext_vector_type(8))) short short8;
typedef __attribute__((ext_vector_type(4))) float floatx4;

#define F_IN 256
#define F_OUT 128

__device__ __forceinline__ short f32_to_bf16_bits(float v) {
    __hip_bfloat16 t = __float2bfloat16(v);
    return *reinterpret_cast<short*>(&t);
}

// Deterministic input-dtype probe.
// flags[0]: 1 = floats are f32, 0 = floats are bf16
// flags[1]: 1 = indices are int64, 0 = int32
__global__ void detect_kernel(const void* __restrict__ featp,
                              const void* __restrict__ dstp,
                              int* __restrict__ flags) {
    if (threadIdx.x == 0 && blockIdx.x == 0) {
        // If feat is f32, bf16-view elements at even index are mantissa junk
        // (uniform exponent). If feat is bf16 N(0,1), nearly all are in a
        // narrow exponent band.
        const unsigned short* fb = (const unsigned short*)featp;
        int plaus = 0;
        for (int i = 0; i < 64; ++i) {
            unsigned short u = fb[2 * i];
            int ex = (u >> 7) & 0xFF;
            if (ex >= 118 && ex <= 137) plaus++;  // |v| in ~[2^-9, 2^10]
        }
        flags[0] = (plaus >= 48) ? 0 : 1;

        // int64 little-endian with values < 2^31: every odd int32 word is 0.
        const int* di = (const int*)dstp;
        int zeros = 0;
        for (int i = 0; i < 64; ++i)
            if (di[2 * i + 1] == 0) zeros++;
        flags[1] = (zeros >= 62) ? 1 : 0;
    }
}

// h[n_nodes][128] = feat[n_nodes][256] @ w[128][256]^T
// Block = 256 threads = 4 waves; each wave does 16 rows x 128 cols via
// 8 n-tiles x 8 k-steps of mfma_f32_16x16x32_bf16.
__global__ __launch_bounds__(256) void gemm_kernel(
    const void* __restrict__ featp, const void* __restrict__ wp,
    void* __restrict__ hp, int n_nodes, int h_f32,
    const int* __restrict__ flags)
{
    const int f32mode = flags[0];
    const int wid  = threadIdx.x >> 6;
    const int lane = threadIdx.x & 63;
    const int m0   = blockIdx.x * 64 + wid * 16;
    const int lrow = min(m0 + (lane & 15), n_nodes - 1);
    const int kg   = lane >> 4;  // k-group 0..3

    short8 a[8];
    if (!f32mode) {
        const short* fr = (const short*)featp + (size_t)lrow * F_IN;
#pragma unroll
        for (int ks = 0; ks < 8; ++ks)
            a[ks] = *(const short8*)(fr + ks * 32 + kg * 8);
    } else {
        const float* fr = (const float*)featp + (size_t)lrow * F_IN;
#pragma unroll
        for (int ks = 0; ks < 8; ++ks) {
            floatx4 v0 = *(const floatx4*)(fr + ks * 32 + kg * 8);
            floatx4 v1 = *(const floatx4*)(fr + ks * 32 + kg * 8 + 4);
            short8 t;
#pragma unroll
            for (int j = 0; j < 4; ++j) {
                t[j]     = f32_to_bf16_bits(v0[j]);
                t[4 + j] = f32_to_bf16_bits(v1[j]);
            }
            a[ks] = t;
        }
    }

    floatx4 acc[8];
#pragma unroll
    for (int nt = 0; nt < 8; ++nt) acc[nt] = (floatx4){0.f, 0.f, 0.f, 0.f};

#pragma unroll
    for (int nt = 0; nt < 8; ++nt) {
        const int wrow = nt * 16 + (lane & 15);
        if (!f32mode) {
            const short* wr = (const short*)wp + (size_t)wrow * F_IN;
#pragma unroll
            for (int ks = 0; ks < 8; ++ks) {
                short8 b = *(const short8*)(wr + ks * 32 + kg * 8);
                acc[nt] = __builtin_amdgcn_mfma_f32_16x16x32_bf16(a[ks], b, acc[nt], 0, 0, 0);
            }
        } else {
            const float* wr = (const float*)wp + (size_t)wrow * F_IN;
#pragma unroll
            for (int ks = 0; ks < 8; ++ks) {
                floatx4 v0 = *(const floatx4*)(wr + ks * 32 + kg * 8);
                floatx4 v1 = *(const floatx4*)(wr + ks * 32 + kg * 8 + 4);
                short8 b;
#pragma unroll
                for (int j = 0; j < 4; ++j) {
                    b[j]     = f32_to_bf16_bits(v0[j]);
                    b[4 + j] = f32_to_bf16_bits(v1[j]);
                }
                acc[nt] = __builtin_amdgcn_mfma_f32_16x16x32_bf16(a[ks], b, acc[nt], 0, 0, 0);
            }
        }
    }

    // C/D layout: col = lane&15, row = (lane>>4)*4 + r  [measured m89]
#pragma unroll
    for (int nt = 0; nt < 8; ++nt) {
        const int col = nt * 16 + (lane & 15);
#pragma unroll
        for (int r = 0; r < 4; ++r) {
            const int orow = m0 + kg * 4 + r;
            if (orow < n_nodes) {
                float v = acc[nt][r];
                if (h_f32)
                    ((float*)hp)[(size_t)orow * F_OUT + col] = v;
                else
                    ((unsigned short*)hp)[(size_t)orow * F_OUT + col] =
                        (unsigned short)f32_to_bf16_bits(v);
            }
        }
    }
}

// One work-item per (edge, col): agg[dst[e]][c] += h[src[e]][c]; deg[dst[e]] += 1.
__global__ __launch_bounds__(256) void scatter_kernel(
    const void* __restrict__ hp, const void* __restrict__ srcp,
    const void* __restrict__ dstp, float* __restrict__ agg,
    float* __restrict__ deg, int n_edges, int n_nodes, int h_f32,
    const int* __restrict__ flags)
{
    const int i64 = flags[1];
    const int total = n_edges * F_OUT;  // 204.8M < INT_MAX
    const int stride = gridDim.x * blockDim.x;
    for (int t = blockIdx.x * blockDim.x + threadIdx.x; t < total; t += stride) {
        const int e = t >> 7;
        const int c = t & 127;
        int s, d;
        if (i64) {
            s = (int)((const long long*)srcp)[e];
            d = (int)((const long long*)dstp)[e];
        } else {
            s = ((const int*)srcp)[e];
            d = ((const int*)dstp)[e];
        }
        if ((unsigned)s >= (unsigned)n_nodes || (unsigned)d >= (unsigned)n_nodes)
            continue;  // safety: never fault on a misdetected index width
        float v;
        if (h_f32) {
            v = ((const float*)hp)[(size_t)s * F_OUT + c];
        } else {
            unsigned x = (unsigned)((const unsigned short*)hp)[(size_t)s * F_OUT + c] << 16;
            v = __builtin_bit_cast(float, x);
        }
        atomicAdd(&agg[(size_t)d * F_OUT + c], v);
        if (c == 0) atomicAdd(&deg[d], 1.0f);
    }
}

__global__ __launch_bounds__(256) void final_kernel(
    const float* __restrict__ agg, const float* __restrict__ deg,
    const void* __restrict__ biasp, void* __restrict__ outp, int n_nodes,
    const int* __restrict__ flags)
{
    const int f32mode = flags[0];
    const int total = n_nodes * F_OUT;
    int t = blockIdx.x * blockDim.x + threadIdx.x;
    if (t >= total) return;
    int n = t >> 7, c = t & 127;
    float scale = 1.0f / fmaxf(deg[n], 1.0f);
    float b = f32mode ? ((const float*)biasp)[c]
                      : __bfloat162float(((const __hip_bfloat16*)biasp)[c]);
    float v = agg[t] * scale + b;
    if (f32mode)
        ((float*)outp)[t] = v;
    else
        ((__hip_bfloat16*)outp)[t] = __float2bfloat16(v);
}

extern "C" void kernel_launch(void* const* d_in, const int* in_sizes, int n_in,
                              void* d_out, int out_size, void* d_ws, size_t ws_size,
                              hipStream_t stream)
{
    const void* feat = d_in[0];
    const void* w    = d_in[1];
    const void* bias = d_in[2];
    const void* src  = d_in[3];
    const void* dst  = d_in[4];
    const int n_nodes = in_sizes[0] / F_IN;   // 100000
    const int n_edges = in_sizes[3];          // 1600000

    char* ws = (char*)d_ws;
    int* flags = (int*)ws;
    const size_t agg_off   = 256;
    const size_t agg_bytes = (size_t)n_nodes * F_OUT * sizeof(float);
    const size_t deg_off   = agg_off + agg_bytes;
    const size_t deg_bytes = (size_t)n_nodes * sizeof(float);
    const size_t h_off     = deg_off + deg_bytes;
    const size_t h_f32_bytes = (size_t)n_nodes * F_OUT * sizeof(float);
    const int h_f32 = (ws_size >= h_off + h_f32_bytes) ? 1 : 0;

    float* agg = (float*)(ws + agg_off);
    float* deg = (float*)(ws + deg_off);
    void*  hp  = (void*)(ws + h_off);

    detect_kernel<<<1, 64, 0, stream>>>(feat, dst, flags);
    hipMemsetAsync(ws + agg_off, 0, agg_bytes + deg_bytes, stream);

    const int gemm_blocks = (n_nodes + 63) / 64;
    gemm_kernel<<<gemm_blocks, 256, 0, stream>>>(feat, w, hp, n_nodes, h_f32, flags);

    const long long total_e = (long long)n_edges * F_OUT;
    const int sblocks = (int)((total_e + 256LL * 8 - 1) / (256LL * 8));
    scatter_kernel<<<sblocks, 256, 0, stream>>>(hp, src, dst, agg, deg,
                                                n_edges, n_nodes, h_f32, flags);

    const int fblocks = (n_nodes * F_OUT + 255) / 256;
    final_kernel<<<fblocks, 256, 0, stream>>>(agg, deg, bias, d_out, n_nodes, flags);
}

// Round 2
// 436.596 us; speedup vs baseline: 2.0993x; 2.0993x over previous
//
#include <hip/hip_runtime.h>
#include <hip/hip_bf16.h>

typedef __attribute__((ext_vector_type(8))) short short8;
typedef __attribute__((ext_vector_type(4))) float floatx4;

#define F_IN 256
#define F_OUT 128

static __device__ __forceinline__ short f32_to_bf16_bits(float v) {
    __hip_bfloat16 t = __float2bfloat16(v);
    return *reinterpret_cast<short*>(&t);
}
static __device__ __forceinline__ float bf16bits_to_f32(unsigned short u) {
    unsigned x = (unsigned)u << 16;
    return __builtin_bit_cast(float, x);
}

// Deterministic input-dtype probe.
// flags[0]: 1 = floats are f32, 0 = floats are bf16
// flags[1]: 1 = indices are int64, 0 = int32
__global__ void detect_kernel(const void* __restrict__ featp,
                              const void* __restrict__ dstp,
                              int* __restrict__ flags) {
    if (threadIdx.x == 0 && blockIdx.x == 0) {
        const unsigned short* fb = (const unsigned short*)featp;
        int plaus = 0;
        for (int i = 0; i < 64; ++i) {
            unsigned short u = fb[2 * i];
            int ex = (u >> 7) & 0xFF;
            if (ex >= 118 && ex <= 137) plaus++;
        }
        flags[0] = (plaus >= 48) ? 0 : 1;

        const int* di = (const int*)dstp;
        int zeros = 0;
        for (int i = 0; i < 64; ++i)
            if (di[2 * i + 1] == 0) zeros++;
        flags[1] = (zeros >= 62) ? 1 : 0;
    }
}

// h[n][128] = feat[n][256] @ w[128][256]^T, h stored bf16.
__global__ __launch_bounds__(256) void gemm_kernel(
    const void* __restrict__ featp, const void* __restrict__ wp,
    unsigned short* __restrict__ hp, int n_nodes,
    const int* __restrict__ flags)
{
    const int f32mode = flags[0];
    const int wid  = threadIdx.x >> 6;
    const int lane = threadIdx.x & 63;
    const int m0   = blockIdx.x * 64 + wid * 16;
    const int lrow = min(m0 + (lane & 15), n_nodes - 1);
    const int kg   = lane >> 4;

    short8 a[8];
    if (!f32mode) {
        const short* fr = (const short*)featp + (size_t)lrow * F_IN;
#pragma unroll
        for (int ks = 0; ks < 8; ++ks)
            a[ks] = *(const short8*)(fr + ks * 32 + kg * 8);
    } else {
        const float* fr = (const float*)featp + (size_t)lrow * F_IN;
#pragma unroll
        for (int ks = 0; ks < 8; ++ks) {
            floatx4 v0 = *(const floatx4*)(fr + ks * 32 + kg * 8);
            floatx4 v1 = *(const floatx4*)(fr + ks * 32 + kg * 8 + 4);
            short8 t;
#pragma unroll
            for (int j = 0; j < 4; ++j) {
                t[j]     = f32_to_bf16_bits(v0[j]);
                t[4 + j] = f32_to_bf16_bits(v1[j]);
            }
            a[ks] = t;
        }
    }

    floatx4 acc[8];
#pragma unroll
    for (int nt = 0; nt < 8; ++nt) acc[nt] = (floatx4){0.f, 0.f, 0.f, 0.f};

#pragma unroll
    for (int nt = 0; nt < 8; ++nt) {
        const int wrow = nt * 16 + (lane & 15);
        if (!f32mode) {
            const short* wr = (const short*)wp + (size_t)wrow * F_IN;
#pragma unroll
            for (int ks = 0; ks < 8; ++ks) {
                short8 b = *(const short8*)(wr + ks * 32 + kg * 8);
                acc[nt] = __builtin_amdgcn_mfma_f32_16x16x32_bf16(a[ks], b, acc[nt], 0, 0, 0);
            }
        } else {
            const float* wr = (const float*)wp + (size_t)wrow * F_IN;
#pragma unroll
            for (int ks = 0; ks < 8; ++ks) {
                floatx4 v0 = *(const floatx4*)(wr + ks * 32 + kg * 8);
                floatx4 v1 = *(const floatx4*)(wr + ks * 32 + kg * 8 + 4);
                short8 b;
#pragma unroll
                for (int j = 0; j < 4; ++j) {
                    b[j]     = f32_to_bf16_bits(v0[j]);
                    b[4 + j] = f32_to_bf16_bits(v1[j]);
                }
                acc[nt] = __builtin_amdgcn_mfma_f32_16x16x32_bf16(a[ks], b, acc[nt], 0, 0, 0);
            }
        }
    }

#pragma unroll
    for (int nt = 0; nt < 8; ++nt) {
        const int col = nt * 16 + (lane & 15);
#pragma unroll
        for (int r = 0; r < 4; ++r) {
            const int orow = m0 + kg * 4 + r;
            if (orow < n_nodes)
                hp[(size_t)orow * F_OUT + col] = (unsigned short)f32_to_bf16_bits(acc[nt][r]);
        }
    }
}

__global__ __launch_bounds__(256) void count_kernel(
    const void* __restrict__ dstp, int* __restrict__ counts,
    int n_edges, int n_nodes, const int* __restrict__ flags)
{
    const int i64 = flags[1];
    const int stride = gridDim.x * blockDim.x;
    for (int e = blockIdx.x * blockDim.x + threadIdx.x; e < n_edges; e += stride) {
        int d = i64 ? (int)((const long long*)dstp)[e] : ((const int*)dstp)[e];
        if ((unsigned)d < (unsigned)n_nodes) atomicAdd(&counts[d], 1);
    }
}

// ---- 3-kernel exclusive scan over counts[n] -> offsets[n] ----
#define SCAN_ITEMS 8
#define SCAN_THREADS 256
#define SCAN_CHUNK (SCAN_ITEMS * SCAN_THREADS)  // 2048

__global__ __launch_bounds__(SCAN_THREADS) void scan1_kernel(
    const int* __restrict__ counts, int* __restrict__ offsets,
    int* __restrict__ blocksums, int n)
{
    __shared__ int lds[SCAN_THREADS];
    const int t = threadIdx.x;
    const int base = blockIdx.x * SCAN_CHUNK + t * SCAN_ITEMS;
    int v[SCAN_ITEMS];
    int run = 0;
#pragma unroll
    for (int j = 0; j < SCAN_ITEMS; ++j) {
        int x = (base + j < n) ? counts[base + j] : 0;
        v[j] = run;       // exclusive within thread
        run += x;
    }
    lds[t] = run;
    __syncthreads();
    // Hillis-Steele inclusive scan over thread sums
    for (int off = 1; off < SCAN_THREADS; off <<= 1) {
        int x = (t >= off) ? lds[t - off] : 0;
        __syncthreads();
        lds[t] += x;
        __syncthreads();
    }
    const int texcl = lds[t] - run;
#pragma unroll
    for (int j = 0; j < SCAN_ITEMS; ++j)
        if (base + j < n) offsets[base + j] = texcl + v[j];
    if (t == SCAN_THREADS - 1) blocksums[blockIdx.x] = lds[t];
}

__global__ void scan2_kernel(int* __restrict__ blocksums, int nb) {
    if (threadIdx.x == 0 && blockIdx.x == 0) {
        int run = 0;
        for (int i = 0; i < nb; ++i) {
            int x = blocksums[i];
            blocksums[i] = run;
            run += x;
        }
    }
}

__global__ __launch_bounds__(SCAN_THREADS) void scan3_kernel(
    int* __restrict__ offsets, int* __restrict__ cursor,
    const int* __restrict__ blocksums, int n)
{
    const int add = blocksums[blockIdx.x];
    const int base = blockIdx.x * SCAN_CHUNK + threadIdx.x * SCAN_ITEMS;
#pragma unroll
    for (int j = 0; j < SCAN_ITEMS; ++j) {
        if (base + j < n) {
            int o = offsets[base + j] + add;
            offsets[base + j] = o;
            cursor[base + j]  = o;
        }
    }
}

__global__ __launch_bounds__(256) void fill_kernel(
    const void* __restrict__ srcp, const void* __restrict__ dstp,
    int* __restrict__ cursor, int* __restrict__ sorted_src,
    int n_edges, int n_nodes, const int* __restrict__ flags)
{
    const int i64 = flags[1];
    const int stride = gridDim.x * blockDim.x;
    for (int e = blockIdx.x * blockDim.x + threadIdx.x; e < n_edges; e += stride) {
        int s, d;
        if (i64) {
            s = (int)((const long long*)srcp)[e];
            d = (int)((const long long*)dstp)[e];
        } else {
            s = ((const int*)srcp)[e];
            d = ((const int*)dstp)[e];
        }
        if ((unsigned)s >= (unsigned)n_nodes || (unsigned)d >= (unsigned)n_nodes)
            continue;
        int pos = atomicAdd(&cursor[d], 1);
        sorted_src[pos] = s;
    }
}

// One wave per node: 64 lanes x 2 cols, register accumulation, no atomics.
__global__ __launch_bounds__(256) void agg_kernel(
    const unsigned short* __restrict__ h, const int* __restrict__ sorted_src,
    const int* __restrict__ offsets, const int* __restrict__ counts,
    const void* __restrict__ biasp, void* __restrict__ outp,
    int n_nodes, const int* __restrict__ flags)
{
    const int f32mode = flags[0];
    const int w = threadIdx.x >> 6;
    const int lane = threadIdx.x & 63;
    const int node = blockIdx.x * 4 + w;
    if (node >= n_nodes) return;

    const int beg = offsets[node];
    const int cnt = counts[node];

    float ax = 0.f, ay = 0.f;
    int i = 0;
    for (; i + 1 < cnt; i += 2) {
        int s0 = sorted_src[beg + i];
        int s1 = sorted_src[beg + i + 1];
        unsigned p0 = *(const unsigned*)(h + (size_t)s0 * F_OUT + lane * 2);
        unsigned p1 = *(const unsigned*)(h + (size_t)s1 * F_OUT + lane * 2);
        ax += bf16bits_to_f32((unsigned short)p0) + bf16bits_to_f32((unsigned short)p1);
        ay += bf16bits_to_f32((unsigned short)(p0 >> 16)) + bf16bits_to_f32((unsigned short)(p1 >> 16));
    }
    if (i < cnt) {
        int s = sorted_src[beg + i];
        unsigned p = *(const unsigned*)(h + (size_t)s * F_OUT + lane * 2);
        ax += bf16bits_to_f32((unsigned short)p);
        ay += bf16bits_to_f32((unsigned short)(p >> 16));
    }

    const float scale = 1.0f / fmaxf((float)cnt, 1.0f);
    float bx, by;
    if (f32mode) {
        bx = ((const float*)biasp)[lane * 2];
        by = ((const float*)biasp)[lane * 2 + 1];
    } else {
        bx = bf16bits_to_f32(((const unsigned short*)biasp)[lane * 2]);
        by = bf16bits_to_f32(((const unsigned short*)biasp)[lane * 2 + 1]);
    }
    float ox = ax * scale + bx;
    float oy = ay * scale + by;

    if (f32mode) {
        ((float*)outp)[(size_t)node * F_OUT + lane * 2]     = ox;
        ((float*)outp)[(size_t)node * F_OUT + lane * 2 + 1] = oy;
    } else {
        unsigned pk = ((unsigned)(unsigned short)f32_to_bf16_bits(oy) << 16) |
                      (unsigned)(unsigned short)f32_to_bf16_bits(ox);
        ((unsigned*)outp)[(size_t)node * F_OUT / 2 + lane] = pk;
    }
}

extern "C" void kernel_launch(void* const* d_in, const int* in_sizes, int n_in,
                              void* d_out, int out_size, void* d_ws, size_t ws_size,
                              hipStream_t stream)
{
    const void* feat = d_in[0];
    const void* w    = d_in[1];
    const void* bias = d_in[2];
    const void* src  = d_in[3];
    const void* dst  = d_in[4];
    const int n_nodes = in_sizes[0] / F_IN;
    const int n_edges = in_sizes[3];

    char* ws = (char*)d_ws;
    auto align256 = [](size_t x) { return (x + 255) & ~(size_t)255; };

    size_t off = 0;
    int* flags = (int*)(ws + off);            off = align256(off + 256);
    int* counts = (int*)(ws + off);           off = align256(off + (size_t)n_nodes * 4);
    int* offsets = (int*)(ws + off);          off = align256(off + (size_t)n_nodes * 4);
    int* cursor = (int*)(ws + off);           off = align256(off + (size_t)n_nodes * 4);
    int* blocksums = (int*)(ws + off);        off = align256(off + 4096);
    int* sorted_src = (int*)(ws + off);       off = align256(off + (size_t)n_edges * 4);
    unsigned short* hp = (unsigned short*)(ws + off);
    off = align256(off + (size_t)n_nodes * F_OUT * 2);
    // off ~= 33.8 MB total

    const int NB1 = (n_nodes + SCAN_CHUNK - 1) / SCAN_CHUNK;

    detect_kernel<<<1, 64, 0, stream>>>(feat, dst, flags);
    hipMemsetAsync(counts, 0, (size_t)n_nodes * 4, stream);

    const int gemm_blocks = (n_nodes + 63) / 64;
    gemm_kernel<<<gemm_blocks, 256, 0, stream>>>(feat, w, hp, n_nodes, flags);

    count_kernel<<<2048, 256, 0, stream>>>(dst, counts, n_edges, n_nodes, flags);
    scan1_kernel<<<NB1, SCAN_THREADS, 0, stream>>>(counts, offsets, blocksums, n_nodes);
    scan2_kernel<<<1, 64, 0, stream>>>(blocksums, NB1);
    scan3_kernel<<<NB1, SCAN_THREADS, 0, stream>>>(offsets, cursor, blocksums, n_nodes);
    fill_kernel<<<2048, 256, 0, stream>>>(src, dst, cursor, sorted_src,
                                          n_edges, n_nodes, flags);

    const int agg_blocks = (n_nodes + 3) / 4;
    agg_kernel<<<agg_blocks, 256, 0, stream>>>(hp, sorted_src, offsets, counts,
                                               bias, d_out, n_nodes, flags);
}